// Round 4
// baseline (785.935 us; speedup 1.0000x reference)
//
#include <hip/hip_runtime.h>
#include <hip/hip_bf16.h>
#include <cstdint>

#define HW 4096
#define MGc 48
#define RECc 5

typedef __attribute__((ext_vector_type(8))) short bf16x8;
typedef __attribute__((ext_vector_type(4))) float f32x4;

__device__ __forceinline__ float sigf(float x) { return 1.f / (1.f + expf(-x)); }
__device__ __forceinline__ float leakyf(float x) { return x >= 0.f ? x : 0.2f * x; }
__device__ __forceinline__ unsigned short f2bfu(float f) {
  __hip_bfloat16 b = __float2bfloat16(f);
  return *reinterpret_cast<unsigned short*>(&b);
}
__device__ __forceinline__ float bfu2f(unsigned short u) {
  unsigned v = ((unsigned)u) << 16;
  return __uint_as_float(v);
}
__device__ __forceinline__ void gload_lds16(const void* g, void* l) {
  __builtin_amdgcn_global_load_lds(
      (const __attribute__((address_space(1))) unsigned int*)g,
      (__attribute__((address_space(3))) unsigned int*)l, 16, 0, 0);
}

// ---------------- K1: rm_sum[b,r,m] = sum_{32x32} rm ----------------
__global__ __launch_bounds__(256) void k_rm_sum(const float* __restrict__ rm,
                                                float* __restrict__ rm_sum) {
  int row = blockIdx.x;  // (b*5+r)*48+m, 15360 rows
  const float4* p = reinterpret_cast<const float4*>(rm + (size_t)row * 1024);
  float4 v = p[threadIdx.x];
  float s = v.x + v.y + v.z + v.w;
  #pragma unroll
  for (int off = 32; off; off >>= 1) s += __shfl_down(s, off);
  __shared__ float sred[4];
  if ((threadIdx.x & 63) == 0) sred[threadIdx.x >> 6] = s;
  __syncthreads();
  if (threadIdx.x == 0) rm_sum[row] = sred[0] + sred[1] + sred[2] + sred[3];
}

// ---------------- K2: q partial sums ----------------
__global__ __launch_bounds__(256) void k_q_part(const float* __restrict__ c,
    const float* __restrict__ ccw, const float* __restrict__ ccb,
    float* __restrict__ q_part) {
  __shared__ float wl[MGc * 64];
  __shared__ float bl[MGc];
  __shared__ float red[4][MGc];
  int b = blockIdx.y, seg = blockIdx.x;
  for (int i = threadIdx.x; i < MGc * 64; i += 256) wl[i] = ccw[i];
  if (threadIdx.x < MGc) bl[threadIdx.x] = ccb[threadIdx.x];
  __syncthreads();
  int px = seg * 256 + threadIdx.x;
  float acc[MGc];
  #pragma unroll
  for (int m = 0; m < MGc; m++) acc[m] = 0.f;
  const float* cp = c + (size_t)b * 64 * HW + px;
  for (int ci = 0; ci < 64; ci++) {
    float v = cp[(size_t)ci * HW];
    #pragma unroll
    for (int m = 0; m < MGc; m++) acc[m] += wl[m * 64 + ci] * v;
  }
  int lane = threadIdx.x & 63, wv = threadIdx.x >> 6;
  #pragma unroll
  for (int m = 0; m < MGc; m++) {
    float t = leakyf(acc[m] + bl[m]);
    #pragma unroll
    for (int off = 32; off; off >>= 1) t += __shfl_down(t, off);
    if (lane == 0) red[wv][m] = t;
  }
  __syncthreads();
  if (threadIdx.x < MGc) {
    float t = red[0][threadIdx.x] + red[1][threadIdx.x] + red[2][threadIdx.x] + red[3][threadIdx.x];
    q_part[((size_t)b * 16 + seg) * MGc + threadIdx.x] = t;
  }
}

// ---------------- K4: mt_pre = attn-weighted rm sum (attn computed in-block) ---------
__global__ __launch_bounds__(256) void k_mt_pre(const float* __restrict__ rm,
    const float* __restrict__ rm_sum, const float* __restrict__ q_part,
    float* __restrict__ mt_pre) {
  __shared__ float sat[RECc];
  int idx = blockIdx.x * 256 + threadIdx.x;
  int b = idx / (MGc * 1024);
  if (threadIdx.x < 64) {
    int lane = threadIdx.x;
    float q = 0.f;
    if (lane < MGc) {
      float s = 0.f;
      for (int sg = 0; sg < 16; sg++) s += q_part[((size_t)b * 16 + sg) * MGc + lane];
      q = s * (1.f / 4096.f);
    }
    float qs = q * q;
    #pragma unroll
    for (int off = 32; off; off >>= 1) qs += __shfl_xor(qs, off);
    float qn = fmaxf(sqrtf(qs), 1e-8f);
    float cosv[RECc];
    #pragma unroll
    for (int r = 0; r < RECc; r++) {
      float m = 0.f;
      if (lane < MGc) m = rm_sum[((size_t)b * RECc + r) * MGc + lane] * (1.f / 1024.f);
      float d = q * m, ms = m * m;
      #pragma unroll
      for (int off = 32; off; off >>= 1) { d += __shfl_xor(d, off); ms += __shfl_xor(ms, off); }
      float mn = fmaxf(sqrtf(ms), 1e-8f);
      cosv[r] = d / (qn * mn);
    }
    float mx = cosv[0];
    #pragma unroll
    for (int r = 1; r < RECc; r++) mx = fmaxf(mx, cosv[r]);
    float ssum = 0.f;
    #pragma unroll
    for (int r = 0; r < RECc; r++) { cosv[r] = expf(cosv[r] - mx); ssum += cosv[r]; }
    float inv = 1.f / ssum;
    #pragma unroll
    for (int r = 0; r < RECc; r++)
      if (lane == r) sat[r] = cosv[r] * inv;
  }
  __syncthreads();
  int rem = idx - b * (MGc * 1024);
  const float* base = rm + (size_t)b * RECc * MGc * 1024 + rem;
  float v = sat[0] * base[0] + sat[1] * base[MGc * 1024] + sat[2] * base[2 * MGc * 1024]
          + sat[3] * base[3 * MGc * 1024] + sat[4] * base[4 * MGc * 1024];
  mt_pre[idx] = v;
}

// ---------------- K5: conv_transpose2d 4x4 s2 p1 + leaky -> mt (bf16) ----------
__global__ __launch_bounds__(512) void k_ssm(const float* __restrict__ mt_pre,
    const float* __restrict__ w, const float* __restrict__ bias,
    __hip_bfloat16* __restrict__ mt) {
  __shared__ float in_t[12][10][20];
  __shared__ float w_t[12][48][16];
  int b = blockIdx.y;
  int tile = blockIdx.x;
  int y0 = (tile >> 1) * 16, x0 = (tile & 1) * 32;
  int wv = threadIdx.x >> 6, lane = threadIdx.x & 63;
  int co0 = wv * 6;
  int oyl = lane >> 2, xseg = lane & 3;
  int oy = y0 + oyl;
  int iy0 = (y0 >> 1) - 1, ix0 = (x0 >> 1) - 1;
  int kyA = (oy + 1) & 1;
  int iyA = (oy + 1 - kyA) >> 1;
  int rA = iyA - iy0, rB = rA - 1;
  float acc[6][8] = {};
  for (int ch = 0; ch < 4; ch++) {
    int ci0 = ch * 12;
    __syncthreads();
    for (int i = threadIdx.x; i < 12 * 10 * 18; i += 512) {
      int ci = i / 180, rr = (i % 180) / 18, cc2 = i % 18;
      int giy = iy0 + rr, gix = ix0 + cc2;
      float v = 0.f;
      if ((unsigned)giy < 32u && (unsigned)gix < 32u)
        v = mt_pre[(((size_t)b * MGc + ci0 + ci) * 32 + giy) * 32 + gix];
      in_t[ci][rr][cc2] = v;
    }
    for (int i = threadIdx.x; i < 12 * 48 * 16; i += 512)
      (&w_t[0][0][0])[i] = w[ci0 * 768 + i];
    __syncthreads();
    #pragma unroll 1
    for (int ci = 0; ci < 12; ci++) {
      float4 a0 = *reinterpret_cast<const float4*>(&in_t[ci][rA][xseg * 4]);
      float4 a1 = *reinterpret_cast<const float4*>(&in_t[ci][rA][xseg * 4 + 4]);
      float4 b0 = *reinterpret_cast<const float4*>(&in_t[ci][rB][xseg * 4]);
      float4 b1 = *reinterpret_cast<const float4*>(&in_t[ci][rB][xseg * 4 + 4]);
      float vA[6] = {a0.x, a0.y, a0.z, a0.w, a1.x, a1.y};
      float vB[6] = {b0.x, b0.y, b0.z, b0.w, b1.x, b1.y};
      #pragma unroll
      for (int co = 0; co < 6; co++) {
        const float* wp = &w_t[ci][co0 + co][0];
        float4 wA = *reinterpret_cast<const float4*>(wp + kyA * 4);
        float4 wB = *reinterpret_cast<const float4*>(wp + (kyA + 2) * 4);
        #pragma unroll
        for (int j = 0; j < 8; j++) {
          if ((j & 1) == 0) {
            int hi = (j >> 1) + 1, lo = j >> 1;
            acc[co][j] += vA[hi] * wA.y + vA[lo] * wA.w + vB[hi] * wB.y + vB[lo] * wB.w;
          } else {
            int hi = ((j + 1) >> 1) + 1, lo = (j + 1) >> 1;
            acc[co][j] += vA[hi] * wA.x + vA[lo] * wA.z + vB[hi] * wB.x + vB[lo] * wB.z;
          }
        }
      }
    }
  }
  int oxb = x0 + xseg * 8;
  #pragma unroll
  for (int co = 0; co < 6; co++) {
    float bb = bias[co0 + co];
    size_t obase = (((size_t)b * MGc + co0 + co) * 64 + oy) * 64 + oxb;
    #pragma unroll
    for (int j = 0; j < 8; j++)
      mt[obase + j] = __float2bfloat16(leakyf(acc[co][j] + bb));
  }
}

// ---------------- K6a: pack concat(x,h) -> P[b][y][x][128ci] bf16 ----------------
__global__ __launch_bounds__(256) void k_ppack(const float* __restrict__ xin,
    const float* __restrict__ hin, __hip_bfloat16* __restrict__ P) {
  __shared__ float t[64][65];
  int b = blockIdx.z, y = blockIdx.y, half = blockIdx.x;
  const float* src = (half ? hin : xin) + (size_t)b * 64 * HW + y * 64;
  #pragma unroll
  for (int it = 0; it < 4; it++) {
    int li = it * 256 + threadIdx.x;
    int ci = li >> 4, x4 = (li & 15) * 4;
    float4 v = *reinterpret_cast<const float4*>(src + (size_t)ci * HW + x4);
    t[x4][ci] = v.x; t[x4 + 1][ci] = v.y; t[x4 + 2][ci] = v.z; t[x4 + 3][ci] = v.w;
  }
  __syncthreads();
  int x = threadIdx.x >> 2, c16 = (threadIdx.x & 3) * 16;
  unsigned short* dst = reinterpret_cast<unsigned short*>(P) +
      (((size_t)b * 4096 + (size_t)y * 64 + x) * 128 + half * 64 + c16);
  bf16x8 o0, o1;
  #pragma unroll
  for (int j = 0; j < 8; j++) {
    o0[j] = (short)f2bfu(t[x][c16 + j]);
    o1[j] = (short)f2bfu(t[x][c16 + 8 + j]);
  }
  *reinterpret_cast<bf16x8*>(dst) = o0;
  *reinterpret_cast<bf16x8*>(dst + 8) = o1;
}

// ---------------- K6b: pack conv_w -> Wp[tap][oc''][ci] bf16 ----------------
// oc'' = nt*80 + gate*16 + ml  <->  oc = gate*64 + nt*16 + ml
__global__ __launch_bounds__(256) void k_wpack(const float* __restrict__ cw,
                                               __hip_bfloat16* __restrict__ Wp) {
  int idx = blockIdx.x * 256 + threadIdx.x;  // 9*320*128 = 368640
  if (idx >= 9 * 320 * 128) return;
  int t = idx / (320 * 128);
  int rem = idx % (320 * 128);
  int ocp = rem / 128, ci = rem % 128;
  int nt = ocp / 80, r2 = ocp % 80, gate = r2 / 16, ml = r2 % 16;
  int oc = gate * 64 + nt * 16 + ml;
  float v = cw[((size_t)oc * 128 + ci) * 9 + t];
  Wp[idx] = __float2bfloat16(v);
}

// ---------------- K6: gates conv3x3 via MFMA, 2-phase pipelined 16-ci chunks ---------
// Block: 512 thr (8 waves), tile = 16 rows x 64 x x 80 oc' (5 gates x 16 m).
// K-space: 8 chunks of 16 ci; per chunk 9 taps x 2 ci8-groups = 18 K-groups.
// MFMA K=32 consumes 4 K-groups: quads q0..q3 full, q4 = (t8,g0),(t8,g1),zero,zero.
// Double-buffered LDS (2x61KB), stage(next) issued BEFORE compute(cur); the only
// vmcnt drain sits at the post-compute barrier (T3-minimum 2-phase).
__global__ __launch_bounds__(512) void k_gates_mfma(
    const __hip_bfloat16* __restrict__ P, const __hip_bfloat16* __restrict__ Wp,
    const float* __restrict__ c, const float* __restrict__ cb,
    float* __restrict__ c_new, __hip_bfloat16* __restrict__ o_g,
    __hip_bfloat16* __restrict__ lam_g) {
  __shared__ bf16x8 s_in[2][36 * 66];  // 2 x 38016 B   unit (L*2+g)*66 + xi
  __shared__ bf16x8 s_w[2][18 * 80];   // 2 x 23040 B   unit (t*2+g)*80 + ol
  // bijective XCD swizzle (nwg = 1024, divisible by 8)
  int orig = blockIdx.y * gridDim.x + blockIdx.x;
  int t_id = (orig & 7) * 128 + (orig >> 3);
  int b = t_id >> 4;
  int ytile = (t_id >> 2) & 3, nt = t_id & 3;
  int y0 = ytile * 16;
  int tid = threadIdx.x;
  int wv = tid >> 6, lane = tid & 63;
  int wr = wv >> 2, xw = wv & 3;
  int lane15 = lane & 15, lq = lane >> 4;
  int rowu = wr * 8;

  // per-lane K-quad fragment offsets: quad q, this lane's K-group j = q*4+lq
  int afq[5], bwq[5];
  #pragma unroll
  for (int q = 0; q < 5; q++) {
    int j = q * 4 + lq;
    int jj = (j < 18) ? j : (j - 2);   // q4 lanes lq>=2: safe finite addr (A zeroed)
    int t = jj >> 1, g = jj & 1;
    int ky = t / 3, dx = t % 3;
    afq[q] = ky * 132 + g * 66 + xw * 16 + lane15 + dx;
    bwq[q] = (t * 2 + g) * 80 + lane15;
  }
  bool a4ok = (lq < 2);

  f32x4 acc[8][5];
  #pragma unroll
  for (int i = 0; i < 8; i++)
    #pragma unroll
    for (int j = 0; j < 5; j++) acc[i][j] = (f32x4)0.f;

  const char* Pb = (const char*)P;
  const char* Wb = (const char*)Wp;

#define STAGE_K(BUF, CC) do {                                                         \
    _Pragma("unroll 1")                                                               \
    for (int u = wv; u < 36; u += 8) {                                                \
      int L = u >> 1, g = u & 1;                                                      \
      int y = y0 - 1 + L;                                                             \
      bf16x8* dst = &s_in[BUF][u * 66];                                               \
      if ((unsigned)y < 64u) {                                                        \
        const char* gp = Pb + ((((size_t)b * 4096 + (size_t)y * 64 + lane) * 128)     \
                               + (CC) * 16 + g * 8) * 2;                              \
        gload_lds16(gp, (void*)(dst + 1));                                            \
        if (lane < 2) dst[lane * 65] = (bf16x8)0;                                     \
      } else {                                                                        \
        dst[lane] = (bf16x8)0;                                                        \
        if (lane < 2) dst[64 + lane] = (bf16x8)0;                                     \
      }                                                                               \
    }                                                                                 \
    _Pragma("unroll 1")                                                               \
    for (int u = wv; u < 23; u += 8) {                                                \
      int e = u * 64 + lane;                                                          \
      if (e < 1440) {                                                                 \
        int unit = e / 80, ol = e % 80;                                               \
        int t = unit >> 1, g = unit & 1;                                              \
        const char* gp = Wb + (((size_t)t * 320 + nt * 80 + ol) * 128                 \
                               + (CC) * 16 + g * 8) * 2;                              \
        gload_lds16(gp, (void*)&s_w[BUF][e]);                                         \
      }                                                                               \
    }                                                                                 \
  } while (0)

#define COMPUTE_K(BUF) do {                                                           \
    _Pragma("unroll")                                                                 \
    for (int q = 0; q < 5; q++) {                                                     \
      bf16x8 af[8];                                                                   \
      _Pragma("unroll")                                                               \
      for (int rr = 0; rr < 8; rr++) {                                                \
        bf16x8 v = s_in[BUF][(rowu + rr) * 132 + afq[q]];                             \
        af[rr] = (q < 4 || a4ok) ? v : (bf16x8)0;                                     \
      }                                                                               \
      bf16x8 bw[5];                                                                   \
      _Pragma("unroll")                                                               \
      for (int gg = 0; gg < 5; gg++) bw[gg] = s_w[BUF][bwq[q] + gg * 16];             \
      __builtin_amdgcn_s_setprio(1);                                                  \
      _Pragma("unroll")                                                               \
      for (int rr = 0; rr < 8; rr++)                                                  \
        _Pragma("unroll")                                                             \
        for (int gg = 0; gg < 5; gg++)                                                \
          acc[rr][gg] = __builtin_amdgcn_mfma_f32_16x16x32_bf16(                      \
              af[rr], bw[gg], acc[rr][gg], 0, 0, 0);                                  \
      __builtin_amdgcn_s_setprio(0);                                                  \
    }                                                                                 \
  } while (0)

  STAGE_K(0, 0);
  __syncthreads();
  #pragma unroll 1
  for (int cp = 0; cp < 4; cp++) {
    int cc = cp * 2;
    STAGE_K(1, cc + 1);        // issue next-chunk loads (in flight across compute)
    COMPUTE_K(0);
    __syncthreads();           // single drain point: after compute
    if (cp < 3) STAGE_K(0, cc + 2);
    COMPUTE_K(1);
    __syncthreads();
  }
#undef STAGE_K
#undef COMPUTE_K

  // epilogue: fused LSTM pointwise
  int m_hid = nt * 16 + lane15;
  float bi = cb[m_hid], bff = cb[64 + m_hid], bgg = cb[128 + m_hid],
        bo = cb[192 + m_hid], bl = cb[256 + m_hid];
  int xb = xw * 16 + lq * 4;
  size_t chofs = ((size_t)b * 64 + m_hid) * HW;
  #pragma unroll
  for (int rr = 0; rr < 8; rr++) {
    int y = y0 + wr * 8 + rr;
    size_t pofs = chofs + (size_t)y * 64 + xb;
    f32x4 cold = *reinterpret_cast<const f32x4*>(c + pofs);
    f32x4 cn;
    unsigned short ov[4], lv[4];
    #pragma unroll
    for (int e = 0; e < 4; e++) {
      float i_ = sigf(acc[rr][0][e] + bi);
      float f_ = sigf(acc[rr][1][e] + bff);
      float g_ = tanhf(acc[rr][2][e] + bgg);
      float o_ = sigf(acc[rr][3][e] + bo);
      float l_ = sigf(acc[rr][4][e] + bl);
      cn[e] = f_ * cold[e] + i_ * g_;
      ov[e] = f2bfu(o_);
      lv[e] = f2bfu(l_);
    }
    *reinterpret_cast<f32x4*>(c_new + pofs) = cn;
    ushort4 ovv = {ov[0], ov[1], ov[2], ov[3]};
    ushort4 lvv = {lv[0], lv[1], lv[2], lv[3]};
    *reinterpret_cast<ushort4*>(reinterpret_cast<unsigned short*>(o_g) + pofs) = ovv;
    *reinterpret_cast<ushort4*>(reinterpret_cast<unsigned short*>(lam_g) + pofs) = lvv;
  }
}

// ---------------- K7: convfuse 1x1 + tanh + output blend -> h_out (2 px/thread) ------
__global__ __launch_bounds__(256) void k_fuse(const float* __restrict__ c_new,
    const __hip_bfloat16* __restrict__ mt, const __hip_bfloat16* __restrict__ o_g,
    const __hip_bfloat16* __restrict__ lam_g, const float* __restrict__ h,
    const float* __restrict__ fw, const float* __restrict__ fb,
    float* __restrict__ h_out) {
  __shared__ float wl[112][64];
  int b = blockIdx.y, seg = blockIdx.x;  // 8 segs of 512 px
  for (int i = threadIdx.x; i < 112 * 64; i += 256) {
    int ci = i >> 6, co = i & 63;
    wl[ci][co] = fw[co * 112 + ci];
  }
  __syncthreads();
  int px = seg * 512 + threadIdx.x * 2;
  size_t bofs = (size_t)b * 64 * HW;
  float2 acc[64];
  #pragma unroll
  for (int co = 0; co < 64; co++) { float bv = fb[co]; acc[co].x = bv; acc[co].y = bv; }
  #pragma unroll 1
  for (int ci = 0; ci < 64; ci++) {
    float2 v = *reinterpret_cast<const float2*>(c_new + bofs + (size_t)ci * HW + px);
    #pragma unroll
    for (int c4 = 0; c4 < 16; c4++) {
      float4 w = *reinterpret_cast<const float4*>(&wl[ci][c4 * 4]);
      acc[c4 * 4 + 0].x += w.x * v.x; acc[c4 * 4 + 0].y += w.x * v.y;
      acc[c4 * 4 + 1].x += w.y * v.x; acc[c4 * 4 + 1].y += w.y * v.y;
      acc[c4 * 4 + 2].x += w.z * v.x; acc[c4 * 4 + 2].y += w.z * v.y;
      acc[c4 * 4 + 3].x += w.w * v.x; acc[c4 * 4 + 3].y += w.w * v.y;
    }
  }
  const unsigned short* mtu = reinterpret_cast<const unsigned short*>(mt);
  size_t mtofs = (size_t)b * MGc * HW + px;
  #pragma unroll 1
  for (int ci = 0; ci < 48; ci++) {
    unsigned u = *reinterpret_cast<const unsigned*>(mtu + mtofs + (size_t)ci * HW);
    float vx = bfu2f((unsigned short)(u & 0xffff));
    float vy = bfu2f((unsigned short)(u >> 16));
    #pragma unroll
    for (int c4 = 0; c4 < 16; c4++) {
      float4 w = *reinterpret_cast<const float4*>(&wl[64 + ci][c4 * 4]);
      acc[c4 * 4 + 0].x += w.x * vx; acc[c4 * 4 + 0].y += w.x * vy;
      acc[c4 * 4 + 1].x += w.y * vx; acc[c4 * 4 + 1].y += w.y * vy;
      acc[c4 * 4 + 2].x += w.z * vx; acc[c4 * 4 + 2].y += w.z * vy;
      acc[c4 * 4 + 3].x += w.w * vx; acc[c4 * 4 + 3].y += w.w * vy;
    }
  }
  const unsigned short* ou = reinterpret_cast<const unsigned short*>(o_g);
  const unsigned short* lu = reinterpret_cast<const unsigned short*>(lam_g);
  #pragma unroll
  for (int co = 0; co < 64; co++) {
    size_t ofs = bofs + (size_t)co * HW + px;
    unsigned uo = *reinterpret_cast<const unsigned*>(ou + ofs);
    unsigned ul = *reinterpret_cast<const unsigned*>(lu + ofs);
    float2 hv = *reinterpret_cast<const float2*>(h + ofs);
    float hnx = tanhf(acc[co].x), hny = tanhf(acc[co].y);
    float ox = bfu2f((unsigned short)(uo & 0xffff)), oy = bfu2f((unsigned short)(uo >> 16));
    float lx = bfu2f((unsigned short)(ul & 0xffff)), ly = bfu2f((unsigned short)(ul >> 16));
    float2 r;
    r.x = lx * (ox * hnx) + (1.f - lx) * hv.x;
    r.y = ly * (oy * hny) + (1.f - ly) * hv.y;
    *reinterpret_cast<float2*>(h_out + ofs) = r;
  }
}

extern "C" void kernel_launch(void* const* d_in, const int* in_sizes, int n_in,
                              void* d_out, int out_size, void* d_ws, size_t ws_size,
                              hipStream_t stream) {
  const float* x   = (const float*)d_in[0];
  const float* h   = (const float*)d_in[1];
  const float* c   = (const float*)d_in[2];
  const float* rm  = (const float*)d_in[3];
  const float* cw  = (const float*)d_in[4];
  const float* cb  = (const float*)d_in[5];
  const float* ccw = (const float*)d_in[6];
  const float* ccb = (const float*)d_in[7];
  const float* sw  = (const float*)d_in[8];
  const float* sb  = (const float*)d_in[9];
  const float* fw  = (const float*)d_in[10];
  const float* fb  = (const float*)d_in[11];

  float* h_out = (float*)d_out;
  float* c_new = h_out + (size_t)16777216;

  char* ws = (char*)d_ws;
  float* rm_sum = (float*)(ws + 0);
  float* q_part = (float*)(ws + 65536);
  float* mt_pre = (float*)(ws + 327680);
  __hip_bfloat16* mt    = (__hip_bfloat16*)(ws + 12910592);
  __hip_bfloat16* o_g   = (__hip_bfloat16*)(ws + 38076416);
  __hip_bfloat16* lam_g = (__hip_bfloat16*)(ws + 71630848);
  __hip_bfloat16* P     = (__hip_bfloat16*)(ws + 105185280);   // 67,108,864 B
  __hip_bfloat16* Wp    = (__hip_bfloat16*)(ws + 172294144);   // 737,280 B

  k_wpack<<<1440, 256, 0, stream>>>(cw, Wp);
  k_ppack<<<dim3(2, 64, 64), 256, 0, stream>>>(x, h, P);
  k_rm_sum<<<15360, 256, 0, stream>>>(rm, rm_sum);
  k_q_part<<<dim3(16, 64), 256, 0, stream>>>(c, ccw, ccb, q_part);
  k_mt_pre<<<12288, 256, 0, stream>>>(rm, rm_sum, q_part, mt_pre);
  k_ssm<<<dim3(8, 64), 512, 0, stream>>>(mt_pre, sw, sb, mt);
  k_gates_mfma<<<dim3(16, 64), 512, 0, stream>>>(P, Wp, c, cb, c_new, o_g, lam_g);
  k_fuse<<<dim3(8, 64), 256, 0, stream>>>(c_new, mt, o_g, lam_g, h, fw, fb, h_out);
}

// Round 6
// 783.705 us; speedup vs baseline: 1.0028x; 1.0028x over previous
//
#include <hip/hip_runtime.h>
#include <hip/hip_bf16.h>
#include <cstdint>

#define HW 4096
#define MGc 48
#define RECc 5

typedef __attribute__((ext_vector_type(8))) short bf16x8;
typedef __attribute__((ext_vector_type(4))) float f32x4;

__device__ __forceinline__ float sigf(float x) { return 1.f / (1.f + expf(-x)); }
__device__ __forceinline__ float leakyf(float x) { return x >= 0.f ? x : 0.2f * x; }
__device__ __forceinline__ unsigned short f2bfu(float f) {
  __hip_bfloat16 b = __float2bfloat16(f);
  return *reinterpret_cast<unsigned short*>(&b);
}
__device__ __forceinline__ float bfu2f(unsigned short u) {
  unsigned v = ((unsigned)u) << 16;
  return __uint_as_float(v);
}
__device__ __forceinline__ void gload_lds16(const void* g, void* l) {
  __builtin_amdgcn_global_load_lds(
      (const __attribute__((address_space(1))) unsigned int*)g,
      (__attribute__((address_space(3))) unsigned int*)l, 16, 0, 0);
}

// ---------------- K0: k_prep = wpack (blocks 0..1439) + P border zero (1440..2479) ----
// Wp[tap][oc''][ci]; oc'' = nt*80 + gate*16 + ml <-> oc = gate*64 + nt*16 + ml
// Pp layout: [b][66][66][128] bf16 (y,x halo of 1, zeroed here).
__global__ __launch_bounds__(256) void k_prep(const float* __restrict__ cw,
    __hip_bfloat16* __restrict__ Wp, __hip_bfloat16* __restrict__ Pp) {
  if (blockIdx.x < 1440) {
    int idx = blockIdx.x * 256 + threadIdx.x;  // < 368640 = 9*320*128
    int t = idx / (320 * 128);
    int rem = idx % (320 * 128);
    int ocp = rem / 128, ci = rem % 128;
    int nt = ocp / 80, r2 = ocp % 80, gate = r2 / 16, ml = r2 % 16;
    int oc = gate * 64 + nt * 16 + ml;
    Wp[idx] = __float2bfloat16(cw[((size_t)oc * 128 + ci) * 9 + t]);
  } else {
    int idx = (blockIdx.x - 1440) * 256 + threadIdx.x;  // < 266240 = 64*4160
    int b = idx / 4160, i = idx % 4160;
    bf16x8* base = reinterpret_cast<bf16x8*>(Pp);
    size_t u;
    if (i < 2112) {               // rows y'=0,65: 2 x 1056 x8-units
      int r = (i < 1056) ? 0 : 65;
      int j = (i < 1056) ? i : i - 1056;
      u = ((size_t)b * 66 + r) * 1056 + j;
    } else {                      // cols x'=0,65 for y'=1..64: 64 rows x 32 units
      int i2 = i - 2112;
      int row = 1 + (i2 >> 5), k = i2 & 31;
      int px = (k < 16) ? 0 : 65, ci8 = k & 15;
      u = (((size_t)b * 66 + row) * 66 + px) * 16 + ci8;
    }
    base[u] = (bf16x8)0;
  }
}

// ---------------- K1: rm_sum[b,r,m] = sum_{32x32} rm ----------------
__global__ __launch_bounds__(256) void k_rm_sum(const float* __restrict__ rm,
                                                float* __restrict__ rm_sum) {
  int row = blockIdx.x;  // (b*5+r)*48+m, 15360 rows
  const float4* p = reinterpret_cast<const float4*>(rm + (size_t)row * 1024);
  float4 v = p[threadIdx.x];
  float s = v.x + v.y + v.z + v.w;
  #pragma unroll
  for (int off = 32; off; off >>= 1) s += __shfl_down(s, off);
  __shared__ float sred[4];
  if ((threadIdx.x & 63) == 0) sred[threadIdx.x >> 6] = s;
  __syncthreads();
  if (threadIdx.x == 0) rm_sum[row] = sred[0] + sred[1] + sred[2] + sred[3];
}

// ---------------- K2: q partial sums ----------------
__global__ __launch_bounds__(256) void k_q_part(const float* __restrict__ c,
    const float* __restrict__ ccw, const float* __restrict__ ccb,
    float* __restrict__ q_part) {
  __shared__ float wl[MGc * 64];
  __shared__ float bl[MGc];
  __shared__ float red[4][MGc];
  int b = blockIdx.y, seg = blockIdx.x;
  for (int i = threadIdx.x; i < MGc * 64; i += 256) wl[i] = ccw[i];
  if (threadIdx.x < MGc) bl[threadIdx.x] = ccb[threadIdx.x];
  __syncthreads();
  int px = seg * 256 + threadIdx.x;
  float acc[MGc];
  #pragma unroll
  for (int m = 0; m < MGc; m++) acc[m] = 0.f;
  const float* cp = c + (size_t)b * 64 * HW + px;
  for (int ci = 0; ci < 64; ci++) {
    float v = cp[(size_t)ci * HW];
    #pragma unroll
    for (int m = 0; m < MGc; m++) acc[m] += wl[m * 64 + ci] * v;
  }
  int lane = threadIdx.x & 63, wv = threadIdx.x >> 6;
  #pragma unroll
  for (int m = 0; m < MGc; m++) {
    float t = leakyf(acc[m] + bl[m]);
    #pragma unroll
    for (int off = 32; off; off >>= 1) t += __shfl_down(t, off);
    if (lane == 0) red[wv][m] = t;
  }
  __syncthreads();
  if (threadIdx.x < MGc) {
    float t = red[0][threadIdx.x] + red[1][threadIdx.x] + red[2][threadIdx.x] + red[3][threadIdx.x];
    q_part[((size_t)b * 16 + seg) * MGc + threadIdx.x] = t;
  }
}

// ---------------- K4: mt_pre = attn-weighted rm sum (attn computed in-block) ---------
__global__ __launch_bounds__(256) void k_mt_pre(const float* __restrict__ rm,
    const float* __restrict__ rm_sum, const float* __restrict__ q_part,
    float* __restrict__ mt_pre) {
  __shared__ float sat[RECc];
  int idx = blockIdx.x * 256 + threadIdx.x;
  int b = idx / (MGc * 1024);
  if (threadIdx.x < 64) {
    int lane = threadIdx.x;
    float q = 0.f;
    if (lane < MGc) {
      float s = 0.f;
      for (int sg = 0; sg < 16; sg++) s += q_part[((size_t)b * 16 + sg) * MGc + lane];
      q = s * (1.f / 4096.f);
    }
    float qs = q * q;
    #pragma unroll
    for (int off = 32; off; off >>= 1) qs += __shfl_xor(qs, off);
    float qn = fmaxf(sqrtf(qs), 1e-8f);
    float cosv[RECc];
    #pragma unroll
    for (int r = 0; r < RECc; r++) {
      float m = 0.f;
      if (lane < MGc) m = rm_sum[((size_t)b * RECc + r) * MGc + lane] * (1.f / 1024.f);
      float d = q * m, ms = m * m;
      #pragma unroll
      for (int off = 32; off; off >>= 1) { d += __shfl_xor(d, off); ms += __shfl_xor(ms, off); }
      float mn = fmaxf(sqrtf(ms), 1e-8f);
      cosv[r] = d / (qn * mn);
    }
    float mx = cosv[0];
    #pragma unroll
    for (int r = 1; r < RECc; r++) mx = fmaxf(mx, cosv[r]);
    float ssum = 0.f;
    #pragma unroll
    for (int r = 0; r < RECc; r++) { cosv[r] = expf(cosv[r] - mx); ssum += cosv[r]; }
    float inv = 1.f / ssum;
    #pragma unroll
    for (int r = 0; r < RECc; r++)
      if (lane == r) sat[r] = cosv[r] * inv;
  }
  __syncthreads();
  int rem = idx - b * (MGc * 1024);
  const float* base = rm + (size_t)b * RECc * MGc * 1024 + rem;
  float v = sat[0] * base[0] + sat[1] * base[MGc * 1024] + sat[2] * base[2 * MGc * 1024]
          + sat[3] * base[3 * MGc * 1024] + sat[4] * base[4 * MGc * 1024];
  mt_pre[idx] = v;
}

// ---------------- K5: conv_transpose2d 4x4 s2 p1 + leaky -> mt (bf16) ----------
__global__ __launch_bounds__(512) void k_ssm(const float* __restrict__ mt_pre,
    const float* __restrict__ w, const float* __restrict__ bias,
    __hip_bfloat16* __restrict__ mt) {
  __shared__ float in_t[12][10][20];
  __shared__ float w_t[12][48][16];
  int b = blockIdx.y;
  int tile = blockIdx.x;
  int y0 = (tile >> 1) * 16, x0 = (tile & 1) * 32;
  int wv = threadIdx.x >> 6, lane = threadIdx.x & 63;
  int co0 = wv * 6;
  int oyl = lane >> 2, xseg = lane & 3;
  int oy = y0 + oyl;
  int iy0 = (y0 >> 1) - 1, ix0 = (x0 >> 1) - 1;
  int kyA = (oy + 1) & 1;
  int iyA = (oy + 1 - kyA) >> 1;
  int rA = iyA - iy0, rB = rA - 1;
  float acc[6][8] = {};
  for (int ch = 0; ch < 4; ch++) {
    int ci0 = ch * 12;
    __syncthreads();
    for (int i = threadIdx.x; i < 12 * 10 * 18; i += 512) {
      int ci = i / 180, rr = (i % 180) / 18, cc2 = i % 18;
      int giy = iy0 + rr, gix = ix0 + cc2;
      float v = 0.f;
      if ((unsigned)giy < 32u && (unsigned)gix < 32u)
        v = mt_pre[(((size_t)b * MGc + ci0 + ci) * 32 + giy) * 32 + gix];
      in_t[ci][rr][cc2] = v;
    }
    for (int i = threadIdx.x; i < 12 * 48 * 16; i += 512)
      (&w_t[0][0][0])[i] = w[ci0 * 768 + i];
    __syncthreads();
    #pragma unroll 1
    for (int ci = 0; ci < 12; ci++) {
      float4 a0 = *reinterpret_cast<const float4*>(&in_t[ci][rA][xseg * 4]);
      float4 a1 = *reinterpret_cast<const float4*>(&in_t[ci][rA][xseg * 4 + 4]);
      float4 b0 = *reinterpret_cast<const float4*>(&in_t[ci][rB][xseg * 4]);
      float4 b1 = *reinterpret_cast<const float4*>(&in_t[ci][rB][xseg * 4 + 4]);
      float vA[6] = {a0.x, a0.y, a0.z, a0.w, a1.x, a1.y};
      float vB[6] = {b0.x, b0.y, b0.z, b0.w, b1.x, b1.y};
      #pragma unroll
      for (int co = 0; co < 6; co++) {
        const float* wp = &w_t[ci][co0 + co][0];
        float4 wA = *reinterpret_cast<const float4*>(wp + kyA * 4);
        float4 wB = *reinterpret_cast<const float4*>(wp + (kyA + 2) * 4);
        #pragma unroll
        for (int j = 0; j < 8; j++) {
          if ((j & 1) == 0) {
            int hi = (j >> 1) + 1, lo = j >> 1;
            acc[co][j] += vA[hi] * wA.y + vA[lo] * wA.w + vB[hi] * wB.y + vB[lo] * wB.w;
          } else {
            int hi = ((j + 1) >> 1) + 1, lo = (j + 1) >> 1;
            acc[co][j] += vA[hi] * wA.x + vA[lo] * wA.z + vB[hi] * wB.x + vB[lo] * wB.z;
          }
        }
      }
    }
  }
  int oxb = x0 + xseg * 8;
  #pragma unroll
  for (int co = 0; co < 6; co++) {
    float bb = bias[co0 + co];
    size_t obase = (((size_t)b * MGc + co0 + co) * 64 + oy) * 64 + oxb;
    #pragma unroll
    for (int j = 0; j < 8; j++)
      mt[obase + j] = __float2bfloat16(leakyf(acc[co][j] + bb));
  }
}

// ---------------- K6a: pack concat(x,h) -> Pp[b][y+1][x+1][128ci] bf16 (padded) ------
__global__ __launch_bounds__(256) void k_ppack(const float* __restrict__ xin,
    const float* __restrict__ hin, __hip_bfloat16* __restrict__ Pp) {
  __shared__ float t[64][65];
  int b = blockIdx.z, y = blockIdx.y, half = blockIdx.x;
  const float* src = (half ? hin : xin) + (size_t)b * 64 * HW + y * 64;
  #pragma unroll
  for (int it = 0; it < 4; it++) {
    int li = it * 256 + threadIdx.x;
    int ci = li >> 4, x4 = (li & 15) * 4;
    float4 v = *reinterpret_cast<const float4*>(src + (size_t)ci * HW + x4);
    t[x4][ci] = v.x; t[x4 + 1][ci] = v.y; t[x4 + 2][ci] = v.z; t[x4 + 3][ci] = v.w;
  }
  __syncthreads();
  int x = threadIdx.x >> 2, c16 = (threadIdx.x & 3) * 16;
  unsigned short* dst = reinterpret_cast<unsigned short*>(Pp) +
      ((((size_t)b * 66 + y + 1) * 66 + x + 1) * 128 + half * 64 + c16);
  bf16x8 o0, o1;
  #pragma unroll
  for (int j = 0; j < 8; j++) {
    o0[j] = (short)f2bfu(t[x][c16 + j]);
    o1[j] = (short)f2bfu(t[x][c16 + 8 + j]);
  }
  *reinterpret_cast<bf16x8*>(dst) = o0;
  *reinterpret_cast<bf16x8*>(dst + 8) = o1;
}

// ---------------- K6: gates conv3x3 via MFMA; A direct-from-global (padded P) --------
// Block: 512 thr (8 waves), tile = 16 rows x 64 x x 80 oc' (5 gates x 16 m).
// LDS = weights only (45KB, single-buffered) -> 2-3 blocks/CU; A-fragments are
// per-lane 16B global loads from L2-resident padded P, 2-deep register rotation.
__global__ __launch_bounds__(512) void k_gates_mfma(
    const __hip_bfloat16* __restrict__ Pp, const __hip_bfloat16* __restrict__ Wp,
    const float* __restrict__ c, const float* __restrict__ cb,
    float* __restrict__ c_new, __hip_bfloat16* __restrict__ o_g,
    __hip_bfloat16* __restrict__ lam_g) {
  __shared__ bf16x8 s_w[9 * 4 * 80];    // 46080 B
  // bijective XCD swizzle (nwg = 1024, divisible by 8)
  int orig = blockIdx.y * gridDim.x + blockIdx.x;
  int t_id = (orig & 7) * 128 + (orig >> 3);
  int b = t_id >> 4;
  int ytile = (t_id >> 2) & 3, nt = t_id & 3;
  int y0 = ytile * 16;
  int tid = threadIdx.x;
  int wv = tid >> 6, lane = tid & 63;
  int wr = wv >> 2, xw = wv & 3;
  int lane15 = lane & 15, lq = lane >> 4;

  // per-lane A base: pixel (b, y'=y0+wr*8, x'=xw*16+lane15), ci8-group lq
  const char* Ab = (const char*)Pp +
      ((((size_t)b * 66 + (y0 + wr * 8)) * 66 + (xw * 16 + lane15)) * 256) + lq * 16;
  // af(ri,dx,cc) = Ab + ri*16896 + dx*256 + cc*64

  f32x4 acc[8][5];
  #pragma unroll
  for (int i = 0; i < 8; i++)
    #pragma unroll
    for (int j = 0; j < 5; j++) acc[i][j] = (f32x4)0.f;

  const char* Wb = (const char*)Wp;

#define COMP(AF, DX) do {                                                             \
    _Pragma("unroll")                                                                 \
    for (int ky = 0; ky < 3; ky++) {                                                  \
      int t = ky * 3 + (DX);                                                          \
      bf16x8 bw[5];                                                                   \
      _Pragma("unroll")                                                               \
      for (int gg = 0; gg < 5; gg++) bw[gg] = s_w[(t * 4 + lq) * 80 + gg * 16 + lane15]; \
      __builtin_amdgcn_s_setprio(1);                                                  \
      _Pragma("unroll")                                                               \
      for (int rr = 0; rr < 8; rr++)                                                  \
        _Pragma("unroll")                                                             \
        for (int gg = 0; gg < 5; gg++)                                                \
          acc[rr][gg] = __builtin_amdgcn_mfma_f32_16x16x32_bf16(                      \
              AF[rr + ky], bw[gg], acc[rr][gg], 0, 0, 0);                             \
      __builtin_amdgcn_s_setprio(0);                                                  \
    }                                                                                 \
  } while (0)

  #pragma unroll 1
  for (int cc = 0; cc < 4; cc++) {
    __syncthreads();   // all waves done reading s_w of previous chunk
    #pragma unroll 1
    for (int u = wv; u < 45; u += 8) {
      int e = u * 64 + lane;
      int t = e / 320, rem = e % 320;
      int g = rem / 80, ol = rem % 80;
      const char* gp = Wb + (((size_t)t * 320 + nt * 80 + ol) * 128 + cc * 32 + g * 8) * 2;
      gload_lds16(gp, (void*)&s_w[e]);
    }
    const char* Ac = Ab + cc * 64;
    bf16x8 afA[10], afB[10];
    #pragma unroll
    for (int ri = 0; ri < 10; ri++)
      afA[ri] = *reinterpret_cast<const bf16x8*>(Ac + ri * 16896);
    __syncthreads();   // weights staged (vmcnt drain also lands afA)
    #pragma unroll
    for (int ri = 0; ri < 10; ri++)
      afB[ri] = *reinterpret_cast<const bf16x8*>(Ac + ri * 16896 + 256);
    COMP(afA, 0);
    #pragma unroll
    for (int ri = 0; ri < 10; ri++)
      afA[ri] = *reinterpret_cast<const bf16x8*>(Ac + ri * 16896 + 512);
    COMP(afB, 1);
    COMP(afA, 2);
  }
#undef COMP

  // epilogue: fused LSTM pointwise
  int m_hid = nt * 16 + lane15;
  float bi = cb[m_hid], bff = cb[64 + m_hid], bgg = cb[128 + m_hid],
        bo = cb[192 + m_hid], bl = cb[256 + m_hid];
  int xb = xw * 16 + lq * 4;
  size_t chofs = ((size_t)b * 64 + m_hid) * HW;
  #pragma unroll
  for (int rr = 0; rr < 8; rr++) {
    int y = y0 + wr * 8 + rr;
    size_t pofs = chofs + (size_t)y * 64 + xb;
    f32x4 cold = *reinterpret_cast<const f32x4*>(c + pofs);
    f32x4 cn;
    unsigned short ov[4], lv[4];
    #pragma unroll
    for (int e = 0; e < 4; e++) {
      float i_ = sigf(acc[rr][0][e] + bi);
      float f_ = sigf(acc[rr][1][e] + bff);
      float g_ = tanhf(acc[rr][2][e] + bgg);
      float o_ = sigf(acc[rr][3][e] + bo);
      float l_ = sigf(acc[rr][4][e] + bl);
      cn[e] = f_ * cold[e] + i_ * g_;
      ov[e] = f2bfu(o_);
      lv[e] = f2bfu(l_);
    }
    *reinterpret_cast<f32x4*>(c_new + pofs) = cn;
    ushort4 ovv = {ov[0], ov[1], ov[2], ov[3]};
    ushort4 lvv = {lv[0], lv[1], lv[2], lv[3]};
    *reinterpret_cast<ushort4*>(reinterpret_cast<unsigned short*>(o_g) + pofs) = ovv;
    *reinterpret_cast<ushort4*>(reinterpret_cast<unsigned short*>(lam_g) + pofs) = lvv;
  }
}

// ---------------- K7: convfuse 1x1 + tanh + output blend -> h_out (2 px/thread) ------
__global__ __launch_bounds__(256) void k_fuse(const float* __restrict__ c_new,
    const __hip_bfloat16* __restrict__ mt, const __hip_bfloat16* __restrict__ o_g,
    const __hip_bfloat16* __restrict__ lam_g, const float* __restrict__ h,
    const float* __restrict__ fw, const float* __restrict__ fb,
    float* __restrict__ h_out) {
  __shared__ float wl[112][64];
  int b = blockIdx.y, seg = blockIdx.x;  // 8 segs of 512 px
  for (int i = threadIdx.x; i < 112 * 64; i += 256) {
    int ci = i >> 6, co = i & 63;
    wl[ci][co] = fw[co * 112 + ci];
  }
  __syncthreads();
  int px = seg * 512 + threadIdx.x * 2;
  size_t bofs = (size_t)b * 64 * HW;
  float2 acc[64];
  #pragma unroll
  for (int co = 0; co < 64; co++) { float bv = fb[co]; acc[co].x = bv; acc[co].y = bv; }
  #pragma unroll 1
  for (int ci = 0; ci < 64; ci++) {
    float2 v = *reinterpret_cast<const float2*>(c_new + bofs + (size_t)ci * HW + px);
    #pragma unroll
    for (int c4 = 0; c4 < 16; c4++) {
      float4 w = *reinterpret_cast<const float4*>(&wl[ci][c4 * 4]);
      acc[c4 * 4 + 0].x += w.x * v.x; acc[c4 * 4 + 0].y += w.x * v.y;
      acc[c4 * 4 + 1].x += w.y * v.x; acc[c4 * 4 + 1].y += w.y * v.y;
      acc[c4 * 4 + 2].x += w.z * v.x; acc[c4 * 4 + 2].y += w.z * v.y;
      acc[c4 * 4 + 3].x += w.w * v.x; acc[c4 * 4 + 3].y += w.w * v.y;
    }
  }
  const unsigned short* mtu = reinterpret_cast<const unsigned short*>(mt);
  size_t mtofs = (size_t)b * MGc * HW + px;
  #pragma unroll 1
  for (int ci = 0; ci < 48; ci++) {
    unsigned u = *reinterpret_cast<const unsigned*>(mtu + mtofs + (size_t)ci * HW);
    float vx = bfu2f((unsigned short)(u & 0xffff));
    float vy = bfu2f((unsigned short)(u >> 16));
    #pragma unroll
    for (int c4 = 0; c4 < 16; c4++) {
      float4 w = *reinterpret_cast<const float4*>(&wl[64 + ci][c4 * 4]);
      acc[c4 * 4 + 0].x += w.x * vx; acc[c4 * 4 + 0].y += w.x * vy;
      acc[c4 * 4 + 1].x += w.y * vx; acc[c4 * 4 + 1].y += w.y * vy;
      acc[c4 * 4 + 2].x += w.z * vx; acc[c4 * 4 + 2].y += w.z * vy;
      acc[c4 * 4 + 3].x += w.w * vx; acc[c4 * 4 + 3].y += w.w * vy;
    }
  }
  const unsigned short* ou = reinterpret_cast<const unsigned short*>(o_g);
  const unsigned short* lu = reinterpret_cast<const unsigned short*>(lam_g);
  #pragma unroll
  for (int co = 0; co < 64; co++) {
    size_t ofs = bofs + (size_t)co * HW + px;
    unsigned uo = *reinterpret_cast<const unsigned*>(ou + ofs);
    unsigned ul = *reinterpret_cast<const unsigned*>(lu + ofs);
    float2 hv = *reinterpret_cast<const float2*>(h + ofs);
    float hnx = tanhf(acc[co].x), hny = tanhf(acc[co].y);
    float ox = bfu2f((unsigned short)(uo & 0xffff)), oy = bfu2f((unsigned short)(uo >> 16));
    float lx = bfu2f((unsigned short)(ul & 0xffff)), ly = bfu2f((unsigned short)(ul >> 16));
    float2 r;
    r.x = lx * (ox * hnx) + (1.f - lx) * hv.x;
    r.y = ly * (oy * hny) + (1.f - ly) * hv.y;
    *reinterpret_cast<float2*>(h_out + ofs) = r;
  }
}

extern "C" void kernel_launch(void* const* d_in, const int* in_sizes, int n_in,
                              void* d_out, int out_size, void* d_ws, size_t ws_size,
                              hipStream_t stream) {
  const float* x   = (const float*)d_in[0];
  const float* h   = (const float*)d_in[1];
  const float* c   = (const float*)d_in[2];
  const float* rm  = (const float*)d_in[3];
  const float* cw  = (const float*)d_in[4];
  const float* cb  = (const float*)d_in[5];
  const float* ccw = (const float*)d_in[6];
  const float* ccb = (const float*)d_in[7];
  const float* sw  = (const float*)d_in[8];
  const float* sb  = (const float*)d_in[9];
  const float* fw  = (const float*)d_in[10];
  const float* fb  = (const float*)d_in[11];

  float* h_out = (float*)d_out;
  float* c_new = h_out + (size_t)16777216;

  // Workspace layout (lifetime-aliased; sizes in bytes):
  //   [0          .. 61,440    ) rm_sum   (live: k_rm_sum -> k_mt_pre)
  //   [65,536     .. 262,144   ) q_part   (live: k_q_part -> k_mt_pre)
  //   [262,144    .. 12,845,056) mt_pre   (live: k_mt_pre -> k_ssm)
  //   [0          .. 33,554,432) o_g      (live: k_gates -> k_fuse)  ALIASES the 3 above
  //   [33,554,432 .. 67,108,864) lam_g    (live: k_gates -> k_fuse)
  //   [67,108,864 .. 92,274,688) mt       (live: k_ssm   -> k_fuse)  25,165,824 B
  //   [92,274,688 ..163,643,392) Pp       (live: k_prep  -> k_gates) 71,368,704 B
  //   [163,643,392..164,380,672) Wp       737,280 B      total ~156.8 MiB
  char* ws = (char*)d_ws;
  float* rm_sum = (float*)(ws + 0);
  float* q_part = (float*)(ws + 65536);
  float* mt_pre = (float*)(ws + 262144);
  __hip_bfloat16* o_g   = (__hip_bfloat16*)(ws + 0);
  __hip_bfloat16* lam_g = (__hip_bfloat16*)(ws + 33554432);
  __hip_bfloat16* mt    = (__hip_bfloat16*)(ws + 67108864);
  __hip_bfloat16* Pp    = (__hip_bfloat16*)(ws + 92274688);
  __hip_bfloat16* Wp    = (__hip_bfloat16*)(ws + 163643392);

  k_prep<<<2480, 256, 0, stream>>>(cw, Wp, Pp);
  k_ppack<<<dim3(2, 64, 64), 256, 0, stream>>>(x, h, Pp);
  k_rm_sum<<<15360, 256, 0, stream>>>(rm, rm_sum);
  k_q_part<<<dim3(16, 64), 256, 0, stream>>>(c, ccw, ccb, q_part);
  k_mt_pre<<<12288, 256, 0, stream>>>(rm, rm_sum, q_part, mt_pre);
  k_ssm<<<dim3(8, 64), 512, 0, stream>>>(mt_pre, sw, sb, mt);
  k_gates_mfma<<<dim3(16, 64), 512, 0, stream>>>(Pp, Wp, c, cb, c_new, o_g, lam_g);
  k_fuse<<<dim3(8, 64), 256, 0, stream>>>(c_new, mt, o_g, lam_g, h, fw, fb, h_out);
}

// Round 7
// 637.060 us; speedup vs baseline: 1.2337x; 1.2302x over previous
//
#include <hip/hip_runtime.h>
#include <hip/hip_bf16.h>
#include <cstdint>

#define HW 4096
#define MGc 48
#define RECc 5

typedef __attribute__((ext_vector_type(8))) short bf16x8;
typedef __attribute__((ext_vector_type(4))) float f32x4;

__device__ __forceinline__ float sigf(float x) { return 1.f / (1.f + expf(-x)); }
__device__ __forceinline__ float leakyf(float x) { return x >= 0.f ? x : 0.2f * x; }
__device__ __forceinline__ unsigned short f2bfu(float f) {
  __hip_bfloat16 b = __float2bfloat16(f);
  return *reinterpret_cast<unsigned short*>(&b);
}
__device__ __forceinline__ float bfu2f(unsigned short u) {
  unsigned v = ((unsigned)u) << 16;
  return __uint_as_float(v);
}
__device__ __forceinline__ void gload_lds16(const void* g, void* l) {
  __builtin_amdgcn_global_load_lds(
      (const __attribute__((address_space(1))) unsigned int*)g,
      (__attribute__((address_space(3))) unsigned int*)l, 16, 0, 0);
}

// ---------------- K0: k_prep = wpack (blocks 0..1439) + P border zero (1440..2479) ----
__global__ __launch_bounds__(256) void k_prep(const float* __restrict__ cw,
    __hip_bfloat16* __restrict__ Wp, __hip_bfloat16* __restrict__ Pp) {
  if (blockIdx.x < 1440) {
    int idx = blockIdx.x * 256 + threadIdx.x;  // < 368640 = 9*320*128
    int t = idx / (320 * 128);
    int rem = idx % (320 * 128);
    int ocp = rem / 128, ci = rem % 128;
    int nt = ocp / 80, r2 = ocp % 80, gate = r2 / 16, ml = r2 % 16;
    int oc = gate * 64 + nt * 16 + ml;
    Wp[idx] = __float2bfloat16(cw[((size_t)oc * 128 + ci) * 9 + t]);
  } else {
    int idx = (blockIdx.x - 1440) * 256 + threadIdx.x;  // < 266240 = 64*4160
    int b = idx / 4160, i = idx % 4160;
    bf16x8* base = reinterpret_cast<bf16x8*>(Pp);
    size_t u;
    if (i < 2112) {               // rows y'=0,65
      int r = (i < 1056) ? 0 : 65;
      int j = (i < 1056) ? i : i - 1056;
      u = ((size_t)b * 66 + r) * 1056 + j;
    } else {                      // cols x'=0,65 for y'=1..64
      int i2 = i - 2112;
      int row = 1 + (i2 >> 5), k = i2 & 31;
      int px = (k < 16) ? 0 : 65, ci8 = k & 15;
      u = (((size_t)b * 66 + row) * 66 + px) * 16 + ci8;
    }
    base[u] = (bf16x8)0;
  }
}

// ---------------- K1: rm_sum[b,r,m] = sum_{32x32} rm ----------------
__global__ __launch_bounds__(256) void k_rm_sum(const float* __restrict__ rm,
                                                float* __restrict__ rm_sum) {
  int row = blockIdx.x;
  const float4* p = reinterpret_cast<const float4*>(rm + (size_t)row * 1024);
  float4 v = p[threadIdx.x];
  float s = v.x + v.y + v.z + v.w;
  #pragma unroll
  for (int off = 32; off; off >>= 1) s += __shfl_down(s, off);
  __shared__ float sred[4];
  if ((threadIdx.x & 63) == 0) sred[threadIdx.x >> 6] = s;
  __syncthreads();
  if (threadIdx.x == 0) rm_sum[row] = sred[0] + sred[1] + sred[2] + sred[3];
}

// ---------------- K2: q partial sums ----------------
__global__ __launch_bounds__(256) void k_q_part(const float* __restrict__ c,
    const float* __restrict__ ccw, const float* __restrict__ ccb,
    float* __restrict__ q_part) {
  __shared__ float wl[MGc * 64];
  __shared__ float bl[MGc];
  __shared__ float red[4][MGc];
  int b = blockIdx.y, seg = blockIdx.x;
  for (int i = threadIdx.x; i < MGc * 64; i += 256) wl[i] = ccw[i];
  if (threadIdx.x < MGc) bl[threadIdx.x] = ccb[threadIdx.x];
  __syncthreads();
  int px = seg * 256 + threadIdx.x;
  float acc[MGc];
  #pragma unroll
  for (int m = 0; m < MGc; m++) acc[m] = 0.f;
  const float* cp = c + (size_t)b * 64 * HW + px;
  for (int ci = 0; ci < 64; ci++) {
    float v = cp[(size_t)ci * HW];
    #pragma unroll
    for (int m = 0; m < MGc; m++) acc[m] += wl[m * 64 + ci] * v;
  }
  int lane = threadIdx.x & 63, wv = threadIdx.x >> 6;
  #pragma unroll
  for (int m = 0; m < MGc; m++) {
    float t = leakyf(acc[m] + bl[m]);
    #pragma unroll
    for (int off = 32; off; off >>= 1) t += __shfl_down(t, off);
    if (lane == 0) red[wv][m] = t;
  }
  __syncthreads();
  if (threadIdx.x < MGc) {
    float t = red[0][threadIdx.x] + red[1][threadIdx.x] + red[2][threadIdx.x] + red[3][threadIdx.x];
    q_part[((size_t)b * 16 + seg) * MGc + threadIdx.x] = t;
  }
}

// ---------------- K4: mt_pre = attn-weighted rm sum (attn computed in-block) ---------
__global__ __launch_bounds__(256) void k_mt_pre(const float* __restrict__ rm,
    const float* __restrict__ rm_sum, const float* __restrict__ q_part,
    float* __restrict__ mt_pre) {
  __shared__ float sat[RECc];
  int idx = blockIdx.x * 256 + threadIdx.x;
  int b = idx / (MGc * 1024);
  if (threadIdx.x < 64) {
    int lane = threadIdx.x;
    float q = 0.f;
    if (lane < MGc) {
      float s = 0.f;
      for (int sg = 0; sg < 16; sg++) s += q_part[((size_t)b * 16 + sg) * MGc + lane];
      q = s * (1.f / 4096.f);
    }
    float qs = q * q;
    #pragma unroll
    for (int off = 32; off; off >>= 1) qs += __shfl_xor(qs, off);
    float qn = fmaxf(sqrtf(qs), 1e-8f);
    float cosv[RECc];
    #pragma unroll
    for (int r = 0; r < RECc; r++) {
      float m = 0.f;
      if (lane < MGc) m = rm_sum[((size_t)b * RECc + r) * MGc + lane] * (1.f / 1024.f);
      float d = q * m, ms = m * m;
      #pragma unroll
      for (int off = 32; off; off >>= 1) { d += __shfl_xor(d, off); ms += __shfl_xor(ms, off); }
      float mn = fmaxf(sqrtf(ms), 1e-8f);
      cosv[r] = d / (qn * mn);
    }
    float mx = cosv[0];
    #pragma unroll
    for (int r = 1; r < RECc; r++) mx = fmaxf(mx, cosv[r]);
    float ssum = 0.f;
    #pragma unroll
    for (int r = 0; r < RECc; r++) { cosv[r] = expf(cosv[r] - mx); ssum += cosv[r]; }
    float inv = 1.f / ssum;
    #pragma unroll
    for (int r = 0; r < RECc; r++)
      if (lane == r) sat[r] = cosv[r] * inv;
  }
  __syncthreads();
  int rem = idx - b * (MGc * 1024);
  const float* base = rm + (size_t)b * RECc * MGc * 1024 + rem;
  float v = sat[0] * base[0] + sat[1] * base[MGc * 1024] + sat[2] * base[2 * MGc * 1024]
          + sat[3] * base[3 * MGc * 1024] + sat[4] * base[4 * MGc * 1024];
  mt_pre[idx] = v;
}

// ---------------- K5: conv_transpose2d 4x4 s2 p1 + leaky -> mt (bf16) ----------
__global__ __launch_bounds__(512) void k_ssm(const float* __restrict__ mt_pre,
    const float* __restrict__ w, const float* __restrict__ bias,
    __hip_bfloat16* __restrict__ mt) {
  __shared__ float in_t[12][10][20];
  __shared__ float w_t[12][48][16];
  int b = blockIdx.y;
  int tile = blockIdx.x;
  int y0 = (tile >> 1) * 16, x0 = (tile & 1) * 32;
  int wv = threadIdx.x >> 6, lane = threadIdx.x & 63;
  int co0 = wv * 6;
  int oyl = lane >> 2, xseg = lane & 3;
  int oy = y0 + oyl;
  int iy0 = (y0 >> 1) - 1, ix0 = (x0 >> 1) - 1;
  int kyA = (oy + 1) & 1;
  int iyA = (oy + 1 - kyA) >> 1;
  int rA = iyA - iy0, rB = rA - 1;
  float acc[6][8] = {};
  for (int ch = 0; ch < 4; ch++) {
    int ci0 = ch * 12;
    __syncthreads();
    for (int i = threadIdx.x; i < 12 * 10 * 18; i += 512) {
      int ci = i / 180, rr = (i % 180) / 18, cc2 = i % 18;
      int giy = iy0 + rr, gix = ix0 + cc2;
      float v = 0.f;
      if ((unsigned)giy < 32u && (unsigned)gix < 32u)
        v = mt_pre[(((size_t)b * MGc + ci0 + ci) * 32 + giy) * 32 + gix];
      in_t[ci][rr][cc2] = v;
    }
    for (int i = threadIdx.x; i < 12 * 48 * 16; i += 512)
      (&w_t[0][0][0])[i] = w[ci0 * 768 + i];
    __syncthreads();
    #pragma unroll 1
    for (int ci = 0; ci < 12; ci++) {
      float4 a0 = *reinterpret_cast<const float4*>(&in_t[ci][rA][xseg * 4]);
      float4 a1 = *reinterpret_cast<const float4*>(&in_t[ci][rA][xseg * 4 + 4]);
      float4 b0 = *reinterpret_cast<const float4*>(&in_t[ci][rB][xseg * 4]);
      float4 b1 = *reinterpret_cast<const float4*>(&in_t[ci][rB][xseg * 4 + 4]);
      float vA[6] = {a0.x, a0.y, a0.z, a0.w, a1.x, a1.y};
      float vB[6] = {b0.x, b0.y, b0.z, b0.w, b1.x, b1.y};
      #pragma unroll
      for (int co = 0; co < 6; co++) {
        const float* wp = &w_t[ci][co0 + co][0];
        float4 wA = *reinterpret_cast<const float4*>(wp + kyA * 4);
        float4 wB = *reinterpret_cast<const float4*>(wp + (kyA + 2) * 4);
        #pragma unroll
        for (int j = 0; j < 8; j++) {
          if ((j & 1) == 0) {
            int hi = (j >> 1) + 1, lo = j >> 1;
            acc[co][j] += vA[hi] * wA.y + vA[lo] * wA.w + vB[hi] * wB.y + vB[lo] * wB.w;
          } else {
            int hi = ((j + 1) >> 1) + 1, lo = (j + 1) >> 1;
            acc[co][j] += vA[hi] * wA.x + vA[lo] * wA.z + vB[hi] * wB.x + vB[lo] * wB.z;
          }
        }
      }
    }
  }
  int oxb = x0 + xseg * 8;
  #pragma unroll
  for (int co = 0; co < 6; co++) {
    float bb = bias[co0 + co];
    size_t obase = (((size_t)b * MGc + co0 + co) * 64 + oy) * 64 + oxb;
    #pragma unroll
    for (int j = 0; j < 8; j++)
      mt[obase + j] = __float2bfloat16(leakyf(acc[co][j] + bb));
  }
}

// ---------------- K6a: pack concat(x,h) -> Pp[b][y+1][x+1][128ci] bf16 (padded) ------
__global__ __launch_bounds__(256) void k_ppack(const float* __restrict__ xin,
    const float* __restrict__ hin, __hip_bfloat16* __restrict__ Pp) {
  __shared__ float t[64][65];
  int b = blockIdx.z, y = blockIdx.y, half = blockIdx.x;
  const float* src = (half ? hin : xin) + (size_t)b * 64 * HW + y * 64;
  #pragma unroll
  for (int it = 0; it < 4; it++) {
    int li = it * 256 + threadIdx.x;
    int ci = li >> 4, x4 = (li & 15) * 4;
    float4 v = *reinterpret_cast<const float4*>(src + (size_t)ci * HW + x4);
    t[x4][ci] = v.x; t[x4 + 1][ci] = v.y; t[x4 + 2][ci] = v.z; t[x4 + 3][ci] = v.w;
  }
  __syncthreads();
  int x = threadIdx.x >> 2, c16 = (threadIdx.x & 3) * 16;
  unsigned short* dst = reinterpret_cast<unsigned short*>(Pp) +
      ((((size_t)b * 66 + y + 1) * 66 + x + 1) * 128 + half * 64 + c16);
  bf16x8 o0, o1;
  #pragma unroll
  for (int j = 0; j < 8; j++) {
    o0[j] = (short)f2bfu(t[x][c16 + j]);
    o1[j] = (short)f2bfu(t[x][c16 + 8 + j]);
  }
  *reinterpret_cast<bf16x8*>(dst) = o0;
  *reinterpret_cast<bf16x8*>(dst + 8) = o1;
}

// ---------------- K6: gates conv3x3 MFMA; 4-wave blocks, 2 blocks/CU -----------------
// Block: 256 thr (4 waves), tile = 16 rows x 16 x x 80 oc (5 gates x 16 m).
// Wave wv owns rows y0+wv*4..+3 (4 row-reps x 5 gates -> acc[4][5] = 80 AGPR).
// LDS: s_in 20.7KB + s_w 45KB = 66KB -> 2 blocks/CU; regs ~140 -> 8 waves/CU.
// Block A's staging drain overlaps block B's MFMA (m114 implicit TLP).
__global__ __launch_bounds__(256) void k_gates_mfma(
    const __hip_bfloat16* __restrict__ Pp, const __hip_bfloat16* __restrict__ Wp,
    const float* __restrict__ c, const float* __restrict__ cb,
    float* __restrict__ c_new, __hip_bfloat16* __restrict__ o_g,
    __hip_bfloat16* __restrict__ lam_g) {
  __shared__ bf16x8 s_in[18 * 4 * 18];  // (L*4+lq)*18 + xi : 20736 B
  __shared__ bf16x8 s_w[9 * 4 * 80];    // (t*4+lq)*80 + ol : 46080 B
  // bijective XCD swizzle (nwg = 4096, divisible by 8)
  int orig = blockIdx.y * gridDim.x + blockIdx.x;
  int t_id = (orig & 7) * 512 + (orig >> 3);
  int b = t_id >> 6;
  int r6 = t_id & 63;
  int ytile = r6 >> 4, xtile = (r6 >> 2) & 3, nt = r6 & 3;
  int y0 = ytile * 16, x0 = xtile * 16;
  int tid = threadIdx.x;
  int wv = tid >> 6, lane = tid & 63;
  int lane15 = lane & 15, lq = lane >> 4;

  f32x4 acc[4][5];
  #pragma unroll
  for (int i = 0; i < 4; i++)
    #pragma unroll
    for (int j = 0; j < 5; j++) acc[i][j] = (f32x4)0.f;

  const char* Pb = (const char*)Pp;
  const char* Wb = (const char*)Wp;

  #pragma unroll 1
  for (int cc = 0; cc < 4; cc++) {
    __syncthreads();   // previous chunk's LDS reads complete
    // stage s_in: 1296 units; e = u*64+lane; padded Pp -> no bounds checks
    #pragma unroll 1
    for (int u = wv; u < 21; u += 4) {
      int e = u * 64 + lane;
      if (e < 1296) {
        int L = e / 72, r = e - L * 72;
        int llq = r / 18, xi = r - llq * 18;
        const char* gp = Pb + ((((size_t)b * 66 + y0 + L) * 66 + (x0 + xi)) * 256)
                         + cc * 64 + llq * 16;
        gload_lds16(gp, (void*)&s_in[e]);
      }
    }
    // stage s_w: 2880 units = 45 wave-groups
    #pragma unroll 1
    for (int u = wv; u < 45; u += 4) {
      int e = u * 64 + lane;
      int unit = e / 80, ol = e - unit * 80;
      int t = unit >> 2, g = unit & 3;
      const char* gp = Wb + (((size_t)t * 320 + nt * 80 + ol) * 128 + cc * 32 + g * 8) * 2;
      gload_lds16(gp, (void*)&s_w[e]);
    }
    __syncthreads();   // drain staging

    #pragma unroll
    for (int dx = 0; dx < 3; dx++) {
      #pragma unroll
      for (int ky = 0; ky < 3; ky++) {
        int t = ky * 3 + dx;
        bf16x8 af[4];
        #pragma unroll
        for (int rr = 0; rr < 4; rr++)
          af[rr] = s_in[((wv * 4 + rr + ky) * 4 + lq) * 18 + lane15 + dx];
        bf16x8 bw[5];
        #pragma unroll
        for (int gg = 0; gg < 5; gg++)
          bw[gg] = s_w[(t * 4 + lq) * 80 + gg * 16 + lane15];
        __builtin_amdgcn_s_setprio(1);
        #pragma unroll
        for (int rr = 0; rr < 4; rr++)
          #pragma unroll
          for (int gg = 0; gg < 5; gg++)
            acc[rr][gg] = __builtin_amdgcn_mfma_f32_16x16x32_bf16(
                af[rr], bw[gg], acc[rr][gg], 0, 0, 0);
        __builtin_amdgcn_s_setprio(0);
      }
    }
  }

  // epilogue: fused LSTM pointwise. C layout: col=lane15 (oc), row=lq*4+e (x offset)
  int m_hid = nt * 16 + lane15;
  float bi = cb[m_hid], bff = cb[64 + m_hid], bgg = cb[128 + m_hid],
        bo = cb[192 + m_hid], bl = cb[256 + m_hid];
  int xb = x0 + lq * 4;
  size_t chofs = ((size_t)b * 64 + m_hid) * HW;
  #pragma unroll
  for (int rr = 0; rr < 4; rr++) {
    int y = y0 + wv * 4 + rr;
    size_t pofs = chofs + (size_t)y * 64 + xb;
    f32x4 cold = *reinterpret_cast<const f32x4*>(c + pofs);
    f32x4 cn;
    unsigned short ov[4], lv[4];
    #pragma unroll
    for (int e = 0; e < 4; e++) {
      float i_ = sigf(acc[rr][0][e] + bi);
      float f_ = sigf(acc[rr][1][e] + bff);
      float g_ = tanhf(acc[rr][2][e] + bgg);
      float o_ = sigf(acc[rr][3][e] + bo);
      float l_ = sigf(acc[rr][4][e] + bl);
      cn[e] = f_ * cold[e] + i_ * g_;
      ov[e] = f2bfu(o_);
      lv[e] = f2bfu(l_);
    }
    *reinterpret_cast<f32x4*>(c_new + pofs) = cn;
    ushort4 ovv = {ov[0], ov[1], ov[2], ov[3]};
    ushort4 lvv = {lv[0], lv[1], lv[2], lv[3]};
    *reinterpret_cast<ushort4*>(reinterpret_cast<unsigned short*>(o_g) + pofs) = ovv;
    *reinterpret_cast<ushort4*>(reinterpret_cast<unsigned short*>(lam_g) + pofs) = lvv;
  }
}

// ---------------- K7: convfuse 1x1 + tanh + output blend -> h_out (2 px/thread) ------
__global__ __launch_bounds__(256) void k_fuse(const float* __restrict__ c_new,
    const __hip_bfloat16* __restrict__ mt, const __hip_bfloat16* __restrict__ o_g,
    const __hip_bfloat16* __restrict__ lam_g, const float* __restrict__ h,
    const float* __restrict__ fw, const float* __restrict__ fb,
    float* __restrict__ h_out) {
  __shared__ float wl[112][64];
  int b = blockIdx.y, seg = blockIdx.x;  // 8 segs of 512 px
  for (int i = threadIdx.x; i < 112 * 64; i += 256) {
    int ci = i >> 6, co = i & 63;
    wl[ci][co] = fw[co * 112 + ci];
  }
  __syncthreads();
  int px = seg * 512 + threadIdx.x * 2;
  size_t bofs = (size_t)b * 64 * HW;
  float2 acc[64];
  #pragma unroll
  for (int co = 0; co < 64; co++) { float bv = fb[co]; acc[co].x = bv; acc[co].y = bv; }
  #pragma unroll 1
  for (int ci = 0; ci < 64; ci++) {
    float2 v = *reinterpret_cast<const float2*>(c_new + bofs + (size_t)ci * HW + px);
    #pragma unroll
    for (int c4 = 0; c4 < 16; c4++) {
      float4 w = *reinterpret_cast<const float4*>(&wl[ci][c4 * 4]);
      acc[c4 * 4 + 0].x += w.x * v.x; acc[c4 * 4 + 0].y += w.x * v.y;
      acc[c4 * 4 + 1].x += w.y * v.x; acc[c4 * 4 + 1].y += w.y * v.y;
      acc[c4 * 4 + 2].x += w.z * v.x; acc[c4 * 4 + 2].y += w.z * v.y;
      acc[c4 * 4 + 3].x += w.w * v.x; acc[c4 * 4 + 3].y += w.w * v.y;
    }
  }
  const unsigned short* mtu = reinterpret_cast<const unsigned short*>(mt);
  size_t mtofs = (size_t)b * MGc * HW + px;
  #pragma unroll 1
  for (int ci = 0; ci < 48; ci++) {
    unsigned u = *reinterpret_cast<const unsigned*>(mtu + mtofs + (size_t)ci * HW);
    float vx = bfu2f((unsigned short)(u & 0xffff));
    float vy = bfu2f((unsigned short)(u >> 16));
    #pragma unroll
    for (int c4 = 0; c4 < 16; c4++) {
      float4 w = *reinterpret_cast<const float4*>(&wl[64 + ci][c4 * 4]);
      acc[c4 * 4 + 0].x += w.x * vx; acc[c4 * 4 + 0].y += w.x * vy;
      acc[c4 * 4 + 1].x += w.y * vx; acc[c4 * 4 + 1].y += w.y * vy;
      acc[c4 * 4 + 2].x += w.z * vx; acc[c4 * 4 + 2].y += w.z * vy;
      acc[c4 * 4 + 3].x += w.w * vx; acc[c4 * 4 + 3].y += w.w * vy;
    }
  }
  const unsigned short* ou = reinterpret_cast<const unsigned short*>(o_g);
  const unsigned short* lu = reinterpret_cast<const unsigned short*>(lam_g);
  #pragma unroll
  for (int co = 0; co < 64; co++) {
    size_t ofs = bofs + (size_t)co * HW + px;
    unsigned uo = *reinterpret_cast<const unsigned*>(ou + ofs);
    unsigned ul = *reinterpret_cast<const unsigned*>(lu + ofs);
    float2 hv = *reinterpret_cast<const float2*>(h + ofs);
    float hnx = tanhf(acc[co].x), hny = tanhf(acc[co].y);
    float ox = bfu2f((unsigned short)(uo & 0xffff)), oy = bfu2f((unsigned short)(uo >> 16));
    float lx = bfu2f((unsigned short)(ul & 0xffff)), ly = bfu2f((unsigned short)(ul >> 16));
    float2 r;
    r.x = lx * (ox * hnx) + (1.f - lx) * hv.x;
    r.y = ly * (oy * hny) + (1.f - ly) * hv.y;
    *reinterpret_cast<float2*>(h_out + ofs) = r;
  }
}

extern "C" void kernel_launch(void* const* d_in, const int* in_sizes, int n_in,
                              void* d_out, int out_size, void* d_ws, size_t ws_size,
                              hipStream_t stream) {
  const float* x   = (const float*)d_in[0];
  const float* h   = (const float*)d_in[1];
  const float* c   = (const float*)d_in[2];
  const float* rm  = (const float*)d_in[3];
  const float* cw  = (const float*)d_in[4];
  const float* cb  = (const float*)d_in[5];
  const float* ccw = (const float*)d_in[6];
  const float* ccb = (const float*)d_in[7];
  const float* sw  = (const float*)d_in[8];
  const float* sb  = (const float*)d_in[9];
  const float* fw  = (const float*)d_in[10];
  const float* fb  = (const float*)d_in[11];

  float* h_out = (float*)d_out;
  float* c_new = h_out + (size_t)16777216;

  // Workspace layout (lifetime-aliased):
  //   [0..61440) rm_sum | [65536..262144) q_part | [262144..12845056) mt_pre
  //   o_g [0..33554432) ALIASES the above (born at k_gates, after they die)
  //   lam_g [33554432..67108864) | mt [67108864..92274688) (25,165,824 B)
  //   Pp [92274688..163643392) (71,368,704 B) | Wp [163643392..164380672)
  char* ws = (char*)d_ws;
  float* rm_sum = (float*)(ws + 0);
  float* q_part = (float*)(ws + 65536);
  float* mt_pre = (float*)(ws + 262144);
  __hip_bfloat16* o_g   = (__hip_bfloat16*)(ws + 0);
  __hip_bfloat16* lam_g = (__hip_bfloat16*)(ws + 33554432);
  __hip_bfloat16* mt    = (__hip_bfloat16*)(ws + 67108864);
  __hip_bfloat16* Pp    = (__hip_bfloat16*)(ws + 92274688);
  __hip_bfloat16* Wp    = (__hip_bfloat16*)(ws + 163643392);

  k_prep<<<2480, 256, 0, stream>>>(cw, Wp, Pp);
  k_ppack<<<dim3(2, 64, 64), 256, 0, stream>>>(x, h, Pp);
  k_rm_sum<<<15360, 256, 0, stream>>>(rm, rm_sum);
  k_q_part<<<dim3(16, 64), 256, 0, stream>>>(c, ccw, ccb, q_part);
  k_mt_pre<<<12288, 256, 0, stream>>>(rm, rm_sum, q_part, mt_pre);
  k_ssm<<<dim3(8, 64), 512, 0, stream>>>(mt_pre, sw, sb, mt);
  k_gates_mfma<<<dim3(64, 64), 256, 0, stream>>>(Pp, Wp, c, cb, c_new, o_g, lam_g);
  k_fuse<<<dim3(8, 64), 256, 0, stream>>>(c_new, mt, o_g, lam_g, h, fw, fb, h_out);
}